// Round 3
// baseline (78.534 us; speedup 1.0000x reference)
//
#include <hip/hip_runtime.h>

#define BATCH     256
#define INPUT_DIM 4096
#define SOMA      2048
#define BRANCHES  16
#define NDEND     32768
#define SAMPLE    32

#define THREADS   512
#define B_T       4                        // batch rows per x-tile (b128 gather)
#define NTILES    8                        // batch tiles per block
#define RPT       (INPUT_DIM / THREADS)    // 8 staging positions per thread

__global__ __launch_bounds__(THREADS, 4)   // cap VGPR at 128 -> 2 blocks/CU
void dendrite_kernel(const float* __restrict__ x,
                     const int*   __restrict__ didx,
                     const float* __restrict__ sw,
                     const float* __restrict__ sb,
                     const float* __restrict__ cw,
                     const float* __restrict__ somab,
                     float* __restrict__ soma_out,   // [BATCH][SOMA]
                     float* __restrict__ dend_out)   // [BATCH][NDEND]
{
    // Transposed x tile: xs[i*4 + bb] = x[b0+bb][i]; one b128 read = 4 batch rows
    __shared__ float xs[INPUT_DIM * B_T];   // 64 KiB

    const int t  = threadIdx.x;
    const int dc = blockIdx.x;   // dendrite chunk (64) — consecutive blocks share bs
    const int bs = blockIdx.y;   // batch super-tile (8)
    const int d  = dc * THREADS + t;        // this thread's dendrite, forever

    // ---- idx/w loaded ONCE into registers ----
    // idx packed as pre-shifted byte offsets (i*16 < 65536) two-per-VGPR: 16 regs
    uint  off[SAMPLE / 2];
    float w[SAMPLE];
    {
        const int4*   ip = (const int4*)  (didx + (size_t)d * SAMPLE);
        const float4* wp = (const float4*)(sw   + (size_t)d * SAMPLE);
        #pragma unroll
        for (int g = 0; g < SAMPLE / 4; ++g) {
            const int4   iv = ip[g];
            const float4 wv = wp[g];
            off[2*g]   = ((uint)iv.x << 4) | ((uint)iv.y << 20);
            off[2*g+1] = ((uint)iv.z << 4) | ((uint)iv.w << 20);
            w[4*g] = wv.x; w[4*g+1] = wv.y; w[4*g+2] = wv.z; w[4*g+3] = wv.w;
        }
    }
    const float bias = sb[d];
    const float cwv  = cw[d];
    const int   n    = d >> 4;
    const float sbi  = somab[n];
    const int   b00  = bs * (B_T * NTILES);

    // ---- prologue: prefetch tile 0 into registers (32 VGPRs) ----
    float4 pf[RPT];
    {
        const float* xp = x + (size_t)b00 * INPUT_DIM;
        #pragma unroll
        for (int r = 0; r < RPT; ++r) {
            const int i = r * THREADS + t;
            pf[r].x = xp[i];
            pf[r].y = xp[i +     INPUT_DIM];
            pf[r].z = xp[i + 2 * INPUT_DIM];
            pf[r].w = xp[i + 3 * INPUT_DIM];
        }
    }

    for (int tile = 0; tile < NTILES; ++tile) {
        const int b0 = b00 + tile * B_T;

        __syncthreads();                    // previous tile's readers done
        // stage: write bank-group = t%8, perfectly even, conflict-free
        #pragma unroll
        for (int r = 0; r < RPT; ++r)
            *(float4*)&xs[(size_t)(r * THREADS + t) * B_T] = pf[r];
        __syncthreads();                    // tile ready (also frees pf regs)

        // issue next tile's prefetch NOW — latency hides under the gather
        if (tile + 1 < NTILES) {
            const float* xp = x + (size_t)(b0 + B_T) * INPUT_DIM;
            #pragma unroll
            for (int r = 0; r < RPT; ++r) {
                const int i = r * THREADS + t;
                pf[r].x = xp[i];
                pf[r].y = xp[i +     INPUT_DIM];
                pf[r].z = xp[i + 2 * INPUT_DIM];
                pf[r].w = xp[i + 3 * INPUT_DIM];
            }
        }

        // ---- gather + FMA: zero global loads, all operands in regs/LDS ----
        float4 acc = {0.f, 0.f, 0.f, 0.f};
        #pragma unroll
        for (int g = 0; g < SAMPLE / 2; ++g) {
            const uint pr = off[g];
            const float4 xv0 = *(const float4*)((const char*)xs + (pr & 0xFFFFu));
            const float4 xv1 = *(const float4*)((const char*)xs + (pr >> 16));
            const float w0 = w[2*g], w1 = w[2*g+1];
            acc.x += xv0.x * w0; acc.y += xv0.y * w0;
            acc.z += xv0.z * w0; acc.w += xv0.w * w0;
            acc.x += xv1.x * w1; acc.y += xv1.y * w1;
            acc.z += xv1.z * w1; acc.w += xv1.w * w1;
        }

        // ---- epilogue: activation, dend store, soma reduce/store ----
        const float a[B_T] = {acc.x, acc.y, acc.z, acc.w};
        float part[B_T];
        #pragma unroll
        for (int bb = 0; bb < B_T; ++bb) {
            const float pre = a[bb] + bias;
            const float act = (pre >= 0.f) ? pre : 0.1f * pre;
            dend_out[(size_t)(b0 + bb) * NDEND + d] = act;   // coalesced
            part[bb] = act * cwv;
        }
        #pragma unroll
        for (int m = 1; m < BRANCHES; m <<= 1) {
            #pragma unroll
            for (int bb = 0; bb < B_T; ++bb)
                part[bb] += __shfl_xor(part[bb], m);
        }
        if ((t & (BRANCHES - 1)) == 0) {
            #pragma unroll
            for (int bb = 0; bb < B_T; ++bb) {
                const float pre = part[bb] + sbi;
                soma_out[(size_t)(b0 + bb) * SOMA + n] = (pre >= 0.f) ? pre : 0.1f * pre;
            }
        }
    }
}

extern "C" void kernel_launch(void* const* d_in, const int* in_sizes, int n_in,
                              void* d_out, int out_size, void* d_ws, size_t ws_size,
                              hipStream_t stream) {
    const float* x     = (const float*)d_in[0];
    const int*   didx  = (const int*)  d_in[1];
    const float* sw    = (const float*)d_in[2];
    const float* sb    = (const float*)d_in[3];
    const float* cw    = (const float*)d_in[4];
    const float* somab = (const float*)d_in[5];

    float* soma_out = (float*)d_out;                     // [256][2048]
    float* dend_out = soma_out + (size_t)BATCH * SOMA;   // [256][32768]

    dim3 grid(NDEND / THREADS, BATCH / (B_T * NTILES)); // (64, 8) = 512 blocks, 2/CU
    dendrite_kernel<<<grid, THREADS, 0, stream>>>(x, didx, sw, sb, cw, somab,
                                                  soma_out, dend_out);
}